// Round 1
// baseline (4333.324 us; speedup 1.0000x reference)
//
#include <hip/hip_runtime.h>
#include <stdint.h>
#include <stddef.h>

#define B_SZ   2
#define N_PTS  15000
#define MPT    1024
#define CSEED  512
#define HMINF (-0.02f)
#define HMAXF (0.06f)

// ---------------------------------------------------------------- mask dtype detect
// mode 0: int32 {0,1}; mode 1: float32 {0.0,1.0}; mode 2: bytes
__global__ void k_detect(const unsigned int* mraw, int* mode_out) {
    __shared__ int vi, vf;
    if (threadIdx.x == 0) { vi = 0; vf = 0; }
    __syncthreads();
    int li = 0, lf = 0;
    for (int i = threadIdx.x; i < (B_SZ * N_PTS) / 4; i += blockDim.x) {
        unsigned int u = mraw[i];                       // safe: 30000 bytes min buffer
        if (u != 0u && u != 1u) li = 1;
        if (u != 0u && u != 0x3F800000u) lf = 1;
    }
    if (li) atomicOr(&vi, 1);
    if (lf) atomicOr(&vf, 1);
    __syncthreads();
    if (threadIdx.x == 0) *mode_out = (vi == 0) ? 0 : ((vf == 0) ? 1 : 2);
}

// ---------------------------------------------------------------- masked FPS
#define FPS_T 1024
#define FPS_K 15

__global__ __launch_bounds__(FPS_T) void k_fps(
        const void* mask_raw, const int* mode_p, const float* seed_xyz,
        float4* cp, int* fps_idx)
{
    const int b   = blockIdx.x;
    const int tid = threadIdx.x;
    const int mode = *mode_p;

    __shared__ int s_cnt[FPS_T];
    __shared__ int s_total;
    __shared__ int s_start;
    __shared__ float s_fx, s_fy, s_fz;
    __shared__ int s_widx;
    __shared__ unsigned long long s_red[FPS_T];

    if (tid == 0) s_start = 0x7fffffff;
    __syncthreads();

    auto rd_mask = [&](int i) -> bool {
        if (mode == 0) return ((const int*)mask_raw)[b * N_PTS + i] != 0;
        if (mode == 1) return ((const unsigned int*)mask_raw)[b * N_PTS + i] != 0u;
        return ((const unsigned char*)mask_raw)[b * N_PTS + i] != 0;
    };

    // count masked points owned by this thread (strided) + global first-masked index
    int cnt = 0, myfirst = 0x7fffffff;
    for (int k = 0; k < FPS_K; ++k) {
        int i = tid + k * FPS_T;
        if (i < N_PTS && rd_mask(i)) { cnt++; if (i < myfirst) myfirst = i; }
    }
    if (myfirst != 0x7fffffff) atomicMin(&s_start, myfirst);
    s_cnt[tid] = cnt;
    __syncthreads();
    if (tid == 0) {                                    // serial exclusive prefix (one-time)
        int run = 0;
        for (int i = 0; i < FPS_T; ++i) { int t = s_cnt[i]; s_cnt[i] = run; run += t; }
        s_total = run;
    }
    __syncthreads();
    int wpos = s_cnt[tid];
    const int Mc = s_total;

    // compact masked points to global scratch (x,y,z,origidx)
    for (int k = 0; k < FPS_K; ++k) {
        int i = tid + k * FPS_T;
        if (i < N_PTS && rd_mask(i)) {
            cp[b * 15008 + wpos] = make_float4(
                seed_xyz[(size_t)(b * N_PTS + i) * 3 + 0],
                seed_xyz[(size_t)(b * N_PTS + i) * 3 + 1],
                seed_xyz[(size_t)(b * N_PTS + i) * 3 + 2],
                __int_as_float(i));
            wpos++;
        }
    }
    __threadfence_block();
    __syncthreads();

    // load my compacted slots into registers
    float px[FPS_K], py[FPS_K], pz[FPS_K], pd[FPS_K];
    int pid[FPS_K];
    const int kmax = (Mc + FPS_T - 1) / FPS_T;         // uniform
    #pragma unroll
    for (int k = 0; k < FPS_K; ++k) {
        int c = tid + k * FPS_T;
        if (k < kmax && c < Mc) {
            float4 v = cp[b * 15008 + c];
            px[k] = v.x; py[k] = v.y; pz[k] = v.z;
            pid[k] = __float_as_int(v.w);
            pd[k] = 1e10f;
        } else {
            px[k] = 0.f; py[k] = 0.f; pz[k] = 0.f; pid[k] = -1; pd[k] = -1.f;
        }
    }
    if (tid == 0) s_widx = s_start;
    __syncthreads();
    {
        int w = s_widx;
        #pragma unroll
        for (int k = 0; k < FPS_K; ++k)
            if (k < kmax && pid[k] == w) { s_fx = px[k]; s_fy = py[k]; s_fz = pz[k]; }
    }
    __syncthreads();

    for (int m = 0; m < MPT; ++m) {
        const float fx = s_fx, fy = s_fy, fz = s_fz;
        if (tid == 0) fps_idx[b * MPT + m] = s_widx;   // sel[m] = far (before update)
        float bval = -2.f; int bidx = 0;
        #pragma unroll
        for (int k = 0; k < FPS_K; ++k) {
            if (k < kmax) {
                // exact np order: (x-f)^2 sub/mul then ((d0+d1)+d2), no fma contraction
                float dx = __fsub_rn(px[k], fx);
                float dy = __fsub_rn(py[k], fy);
                float dz = __fsub_rn(pz[k], fz);
                float d  = __fadd_rn(__fadd_rn(__fmul_rn(dx, dx), __fmul_rn(dy, dy)),
                                     __fmul_rn(dz, dz));
                float nd = fminf(pd[k], d);
                pd[k] = nd;
                bool gt = nd > bval;
                bval = gt ? nd : bval;
                bidx = gt ? pid[k] : bidx;
            }
        }
        // pack (val, ~idx): max -> first-index tie-break like np.argmax
        unsigned long long key = (bval < 0.f) ? 0ull
            : ((((unsigned long long)__float_as_uint(bval)) << 32)
               | (unsigned long long)(unsigned int)(~(unsigned int)bidx));
        s_red[tid] = key;
        __syncthreads();
        if (tid < 64) {
            unsigned long long best = s_red[tid];
            #pragma unroll
            for (int i = 1; i < FPS_T / 64; ++i) {
                unsigned long long o = s_red[tid + i * 64];
                if (o > best) best = o;
            }
            #pragma unroll
            for (int sft = 32; sft >= 1; sft >>= 1) {
                unsigned long long o = __shfl_xor(best, sft, 64);
                if (o > best) best = o;
            }
            if (tid == 0) s_widx = (int)(~(unsigned int)(best & 0xffffffffull));
        }
        __syncthreads();
        {
            int w = s_widx;                            // winner broadcasts its coords
            #pragma unroll
            for (int k = 0; k < FPS_K; ++k)
                if (k < kmax && pid[k] == w) { s_fx = px[k]; s_fy = py[k]; s_fz = pz[k]; }
        }
        __syncthreads();
    }
}

// ---------------------------------------------------------------- gathers
__global__ void k_gather(const float* seed_features, const float* seed_xyz,
                         const int* fps_idx, float* feat_g, float* xyz_g)
{
    int e = blockIdx.x;
    if (e < B_SZ * CSEED) {
        int b = e >> 9, c = e & (CSEED - 1);
        const float* src = seed_features + (size_t)(b * CSEED + c) * N_PTS;
        float* dst = feat_g + (size_t)(b * CSEED + c) * MPT;
        const int* idx = fps_idx + b * MPT;
        for (int m = threadIdx.x; m < MPT; m += blockDim.x) dst[m] = src[idx[m]];
    } else {
        int b = e - B_SZ * CSEED;
        const int* idx = fps_idx + b * MPT;
        for (int m = threadIdx.x; m < MPT; m += blockDim.x) {
            int p = idx[m];
            xyz_g[(size_t)(b * MPT + m) * 3 + 0] = seed_xyz[(size_t)(b * N_PTS + p) * 3 + 0];
            xyz_g[(size_t)(b * MPT + m) * 3 + 1] = seed_xyz[(size_t)(b * N_PTS + p) * 3 + 1];
            xyz_g[(size_t)(b * MPT + m) * 3 + 2] = seed_xyz[(size_t)(b * N_PTS + p) * 3 + 2];
        }
    }
}

// ---------------------------------------------------------------- W2 transpose: w2t[s][c][o]
__global__ void k_w2t(const float* crop_w2, float* w2t) {
    int i = blockIdx.x * blockDim.x + threadIdx.x;
    if (i >= 4 * 512 * 256) return;
    int s = i >> 17;
    int r = i & 131071;
    int c = r >> 9, o = r & 511;
    w2t[i] = crop_w2[(size_t)(s * 512 + o) * 256 + c];
}

// ---------------------------------------------------------------- F1T = feat_g^T * W1f^T + b1
// f1t[(s,b,p), o] = sum_c feat_g[b][c][p] * crop_w1[s][o][3+c] + crop_b1[s][o]
__global__ __launch_bounds__(256) void k_f1(const float* feat_g, const float* crop_w1,
                                            const float* crop_b1, float* f1t)
{
    const int blk = blockIdx.x;
    const int pt = blk & 15;
    const int b  = (blk >> 4) & 1;
    const int s  = blk >> 5;
    const int p0 = pt * 64;
    __shared__ float A[16][64];
    __shared__ float Bm[16][256];
    const int tid = threadIdx.x;
    const int pg = tid & 15, og = tid >> 4;
    float acc[4][16];
    #pragma unroll
    for (int i = 0; i < 4; ++i)
        #pragma unroll
        for (int j = 0; j < 16; ++j) acc[i][j] = 0.f;

    for (int kc = 0; kc < CSEED; kc += 16) {
        __syncthreads();
        {
            int r = tid >> 4, pp = (tid & 15) * 4;
            *(float4*)&A[r][pp] =
                *(const float4*)&feat_g[(size_t)(b * CSEED + kc + r) * MPT + p0 + pp];
            #pragma unroll
            for (int r2 = 0; r2 < 16; ++r2)
                Bm[r2][tid] = crop_w1[(size_t)(s * 256 + tid) * 515 + 3 + kc + r2];
        }
        __syncthreads();
        #pragma unroll
        for (int r = 0; r < 16; ++r) {
            float4 a4 = *(const float4*)&A[r][pg * 4];
            float av[4] = {a4.x, a4.y, a4.z, a4.w};
            float bv[16];
            #pragma unroll
            for (int q = 0; q < 4; ++q) {
                float4 b4 = *(const float4*)&Bm[r][og * 16 + q * 4];
                bv[q*4+0] = b4.x; bv[q*4+1] = b4.y; bv[q*4+2] = b4.z; bv[q*4+3] = b4.w;
            }
            #pragma unroll
            for (int i = 0; i < 4; ++i)
                #pragma unroll
                for (int j = 0; j < 16; ++j)
                    acc[i][j] += av[i] * bv[j];
        }
    }
    #pragma unroll
    for (int i = 0; i < 4; ++i) {
        size_t row = (size_t)((s * B_SZ + b) * MPT + p0 + pg * 4 + i) * 256;
        #pragma unroll
        for (int q = 0; q < 4; ++q) {
            float4 o4;
            o4.x = acc[i][q*4+0] + crop_b1[s*256 + og*16 + q*4+0];
            o4.y = acc[i][q*4+1] + crop_b1[s*256 + og*16 + q*4+1];
            o4.z = acc[i][q*4+2] + crop_b1[s*256 + og*16 + q*4+2];
            o4.w = acc[i][q*4+3] + crop_b1[s*256 + og*16 + q*4+3];
            *(float4*)&f1t[row + og * 16 + q * 4] = o4;
        }
    }
}

// ---------------------------------------------------------------- local coords + neighbor select
// One wave per (b,j). Reproduces stable argsort(~valid)[:ns] + pad-with-first semantics.
__global__ __launch_bounds__(256) void k_select(const float* xyz_g, const float* views_rot,
                                                int* sel_idx, float* sel_xyz)
{
    const int wv = threadIdx.x >> 6;
    const int lane = threadIdx.x & 63;
    const int gj = blockIdx.x * 4 + wv;
    const int b = gj >> 10, j = gj & (MPT - 1);

    const float cx = xyz_g[(size_t)(b * MPT + j) * 3 + 0];
    const float cy = xyz_g[(size_t)(b * MPT + j) * 3 + 1];
    const float cz = xyz_g[(size_t)(b * MPT + j) * 3 + 2];
    const float* R = views_rot + (size_t)(b * MPT + j) * 9;
    const float r00 = R[0], r01 = R[1], r02 = R[2];
    const float r10 = R[3], r11 = R[4], r12 = R[5];
    const float r20 = R[6], r21 = R[7], r22 = R[8];

    const float R2C[4] = { (float)(0.025 * 0.025), (float)(0.0375 * 0.0375),
                           (float)(0.05 * 0.05),   (float)(0.075 * 0.075) };
    const int NSs[4] = {16, 32, 32, 64};

    __shared__ float s_zloc[4][3];
    __shared__ int   s_padk[4][4];
    __shared__ float s_padx[4][4][3];

    int cnt[4] = {0, 0, 0, 0};

    for (int ch = 0; ch < 16; ++ch) {
        int k = ch * 64 + lane;
        float x = xyz_g[(size_t)(b * MPT + k) * 3 + 0];
        float y = xyz_g[(size_t)(b * MPT + k) * 3 + 1];
        float z = xyz_g[(size_t)(b * MPT + k) * 3 + 2];
        float rx = __fsub_rn(x, cx), ry = __fsub_rn(y, cy), rz = __fsub_rn(z, cz);
        float l0 = __fadd_rn(__fadd_rn(__fmul_rn(rx, r00), __fmul_rn(ry, r10)), __fmul_rn(rz, r20));
        float l1 = __fadd_rn(__fadd_rn(__fmul_rn(rx, r01), __fmul_rn(ry, r11)), __fmul_rn(rz, r21));
        float l2 = __fadd_rn(__fadd_rn(__fmul_rn(rx, r02), __fmul_rn(ry, r12)), __fmul_rn(rz, r22));
        float r2 = __fadd_rn(__fmul_rn(l1, l1), __fmul_rn(l2, l2));
        bool inh = (l0 >= HMINF) && (l0 <= HMAXF);
        if (ch == 0 && lane == 0) { s_zloc[wv][0] = l0; s_zloc[wv][1] = l1; s_zloc[wv][2] = l2; }
        #pragma unroll
        for (int sc = 0; sc < 4; ++sc) {
            bool v = inh && (r2 < R2C[sc]);
            unsigned long long bal = __ballot(v);
            int pre = __popcll(bal & ((1ull << lane) - 1ull));
            int p = cnt[sc] + pre;
            if (v && p < NSs[sc]) {
                size_t sb = ((size_t)(sc * B_SZ + b) * MPT + j) * 64 + p;
                sel_idx[sb] = k;
                sel_xyz[sb * 3 + 0] = l0;
                sel_xyz[sb * 3 + 1] = l1;
                sel_xyz[sb * 3 + 2] = l2;
                if (p == 0) {
                    s_padk[wv][sc] = k;
                    s_padx[wv][sc][0] = l0; s_padx[wv][sc][1] = l1; s_padx[wv][sc][2] = l2;
                }
            }
            cnt[sc] += __popcll(bal);
        }
    }
    __syncthreads();
    #pragma unroll
    for (int sc = 0; sc < 4; ++sc) {
        int cs = cnt[sc];
        int pk; float a0, a1, a2;
        if (cs > 0) { pk = s_padk[wv][sc]; a0 = s_padx[wv][sc][0]; a1 = s_padx[wv][sc][1]; a2 = s_padx[wv][sc][2]; }
        else        { pk = 0; a0 = s_zloc[wv][0]; a1 = s_zloc[wv][1]; a2 = s_zloc[wv][2]; }
        for (int n = cs + lane; n < NSs[sc]; n += 64) {
            size_t sb = ((size_t)(sc * B_SZ + b) * MPT + j) * 64 + n;
            sel_idx[sb] = pk;
            sel_xyz[sb * 3 + 0] = a0; sel_xyz[sb * 3 + 1] = a1; sel_xyz[sb * 3 + 2] = a2;
        }
    }
}

// ---------------------------------------------------------------- crop MLP: h1 assemble + GEMM2 + maxpool
// block = 64 columns (jt centers x ns samples), outputs 512 x jt into vp_cat
__global__ __launch_bounds__(256) void k_crop(
        const int s, const int ns, const int log2ns,
        const float* f1t, const float* crop_w1, const float* w2t, const float* crop_b2,
        const int* sel_idx, const float* sel_xyz, float* vp_cat)
{
    const int tid = threadIdx.x;
    const int jt = 64 >> log2ns;
    const int nj = MPT / jt;
    const int b = blockIdx.x / nj;
    const int jbase = (blockIdx.x % nj) * jt;

    __shared__ float h1[128 * 64];     // [c'][col], half of K at a time  (32KB)
    __shared__ float w2c[8 * 512];     // W2^T chunk [c8][o]              (16KB)
    __shared__ float w1xa[3 * 256];    // layer-1 xyz weights [axis][o]

    for (int i = tid; i < 768; i += 256) {
        int a = i >> 8, o = i & 255;
        w1xa[i] = crop_w1[(size_t)(s * 256 + o) * 515 + a];
    }

    const int col = tid & 63;
    const int cq = tid >> 6;
    const int jl = col >> log2ns;
    const int nn = col & (ns - 1);
    const size_t sb = ((size_t)(s * B_SZ + b) * MPT + jbase + jl) * 64 + nn;
    const int p = sel_idx[sb];
    const float gx = sel_xyz[sb * 3 + 0];
    const float gy = sel_xyz[sb * 3 + 1];
    const float gz = sel_xyz[sb * 3 + 2];
    const float* f1row = f1t + (size_t)((s * B_SZ + b) * MPT + p) * 256;

    const int ogrp = tid >> 3;
    const int cgrp = tid & 7;
    const int o0 = ogrp * 16, col0 = cgrp * 8;
    const float* w2s = w2t + (size_t)s * 256 * 512;

    float acc[16][8];
    #pragma unroll
    for (int i = 0; i < 16; ++i)
        #pragma unroll
        for (int jq = 0; jq < 8; ++jq) acc[i][jq] = 0.f;

    for (int half = 0; half < 2; ++half) {
        __syncthreads();
        // build h1 for c in [half*128, half*128+128)
        #pragma unroll
        for (int cg4 = 0; cg4 < 8; ++cg4) {
            int cpr = cq * 32 + cg4 * 4;
            int c = half * 128 + cpr;
            float4 fv = *(const float4*)&f1row[c];
            float vv[4] = {fv.x, fv.y, fv.z, fv.w};
            #pragma unroll
            for (int q = 0; q < 4; ++q) {
                int c2 = c + q;
                float v = vv[q] + w1xa[c2] * gx + w1xa[256 + c2] * gy + w1xa[512 + c2] * gz;
                h1[(cpr + q) * 64 + col] = fmaxf(v, 0.f);
            }
        }
        __syncthreads();
        for (int cc = 0; cc < 16; ++cc) {
            __syncthreads();
            #pragma unroll
            for (int i = 0; i < 4; ++i) {
                int e = tid + i * 256;
                int r = e >> 7, o4 = (e & 127) * 4;
                *(float4*)&w2c[r * 512 + o4] =
                    *(const float4*)&w2s[(size_t)(half * 128 + cc * 8 + r) * 512 + o4];
            }
            __syncthreads();
            #pragma unroll
            for (int c8 = 0; c8 < 8; ++c8) {
                const float* hp = &h1[(cc * 8 + c8) * 64 + col0];
                float4 b0 = *(const float4*)hp;
                float4 b1 = *(const float4*)(hp + 4);
                const float* ap = &w2c[c8 * 512 + o0];
                float4 a0 = *(const float4*)ap;
                float4 a1 = *(const float4*)(ap + 4);
                float4 a2 = *(const float4*)(ap + 8);
                float4 a3 = *(const float4*)(ap + 12);
                float av[16] = {a0.x,a0.y,a0.z,a0.w, a1.x,a1.y,a1.z,a1.w,
                                a2.x,a2.y,a2.z,a2.w, a3.x,a3.y,a3.z,a3.w};
                float bv[8]  = {b0.x,b0.y,b0.z,b0.w, b1.x,b1.y,b1.z,b1.w};
                #pragma unroll
                for (int oi = 0; oi < 16; ++oi)
                    #pragma unroll
                    for (int ci = 0; ci < 8; ++ci)
                        acc[oi][ci] += av[oi] * bv[ci];
            }
        }
    }
    __syncthreads();
    float* mbuf = w2c;                 // reuse as [o][cgrp] max buffer (512*8)
    #pragma unroll
    for (int oi = 0; oi < 16; ++oi) {
        float mx = acc[oi][0];
        #pragma unroll
        for (int ci = 1; ci < 8; ++ci) mx = fmaxf(mx, acc[oi][ci]);
        mbuf[(o0 + oi) * 8 + cgrp] = mx;
    }
    __syncthreads();
    const int g = ns >> 3;
    for (int t = tid; t < 512 * jt; t += 256) {
        int o = t & 511, jl2 = t >> 9;
        float v = mbuf[o * 8 + jl2 * g];
        for (int q = 1; q < g; ++q) v = fmaxf(v, mbuf[o * 8 + jl2 * g + q]);
        v = fmaxf(v + crop_b2[s * 512 + o], 0.f);   // relu(max + b2) == max(relu(.+b2))
        vp_cat[((size_t)(b * 4 + s) * 512 + o) * MPT + jbase + jl2] = v;
    }
}

// ---------------------------------------------------------------- fuse + gate + output
__global__ __launch_bounds__(256) void k_out(
        const float* vp_cat, const float* feat_g,
        const float* fuse_w, const float* fuse_b,
        const float* gate_w, const float* gate_b, float* out)
{
    const int blk = blockIdx.x;
    const int mt = blk & 15, ot = (blk >> 4) & 3, b = blk >> 6;
    const int o0b = ot * 128, m0b = mt * 64;
    __shared__ float A[16 * 128];
    __shared__ float Bm[16 * 64];
    const int tid = threadIdx.x;
    const int og = tid >> 4, mg = tid & 15;
    float acc1[8][4], acc2[8][4];
    #pragma unroll
    for (int i = 0; i < 8; ++i)
        #pragma unroll
        for (int jq = 0; jq < 4; ++jq) { acc1[i][jq] = 0.f; acc2[i][jq] = 0.f; }

    // pass 1: fused = fuse_w @ vp_cat   (K = 2048)
    for (int kc = 0; kc < 2048; kc += 16) {
        __syncthreads();
        {
            int oo = tid >> 1, r0 = (tid & 1) * 8;
            const float* srow = fuse_w + (size_t)(o0b + oo) * 2048 + kc + r0;
            float4 u0 = *(const float4*)srow;
            float4 u1 = *(const float4*)(srow + 4);
            A[(r0 + 0) * 128 + oo] = u0.x; A[(r0 + 1) * 128 + oo] = u0.y;
            A[(r0 + 2) * 128 + oo] = u0.z; A[(r0 + 3) * 128 + oo] = u0.w;
            A[(r0 + 4) * 128 + oo] = u1.x; A[(r0 + 5) * 128 + oo] = u1.y;
            A[(r0 + 6) * 128 + oo] = u1.z; A[(r0 + 7) * 128 + oo] = u1.w;
            int r = tid >> 4, mm = (tid & 15) * 4;
            *(float4*)&Bm[r * 64 + mm] =
                *(const float4*)&vp_cat[((size_t)b * 2048 + kc + r) * MPT + m0b + mm];
        }
        __syncthreads();
        #pragma unroll
        for (int r = 0; r < 16; ++r) {
            float4 a0 = *(const float4*)&A[r * 128 + og * 8];
            float4 a1 = *(const float4*)&A[r * 128 + og * 8 + 4];
            float4 bb = *(const float4*)&Bm[r * 64 + mg * 4];
            float av[8] = {a0.x,a0.y,a0.z,a0.w, a1.x,a1.y,a1.z,a1.w};
            float bv[4] = {bb.x, bb.y, bb.z, bb.w};
            #pragma unroll
            for (int oi = 0; oi < 8; ++oi)
                #pragma unroll
                for (int mi = 0; mi < 4; ++mi)
                    acc1[oi][mi] += av[oi] * bv[mi];
        }
    }
    // pass 2: gate logits = gate_w @ feat_g   (K = 512)
    for (int kc = 0; kc < 512; kc += 16) {
        __syncthreads();
        {
            int oo = tid >> 1, r0 = (tid & 1) * 8;
            const float* srow = gate_w + (size_t)(o0b + oo) * 512 + kc + r0;
            float4 u0 = *(const float4*)srow;
            float4 u1 = *(const float4*)(srow + 4);
            A[(r0 + 0) * 128 + oo] = u0.x; A[(r0 + 1) * 128 + oo] = u0.y;
            A[(r0 + 2) * 128 + oo] = u0.z; A[(r0 + 3) * 128 + oo] = u0.w;
            A[(r0 + 4) * 128 + oo] = u1.x; A[(r0 + 5) * 128 + oo] = u1.y;
            A[(r0 + 6) * 128 + oo] = u1.z; A[(r0 + 7) * 128 + oo] = u1.w;
            int r = tid >> 4, mm = (tid & 15) * 4;
            *(float4*)&Bm[r * 64 + mm] =
                *(const float4*)&feat_g[((size_t)b * CSEED + kc + r) * MPT + m0b + mm];
        }
        __syncthreads();
        #pragma unroll
        for (int r = 0; r < 16; ++r) {
            float4 a0 = *(const float4*)&A[r * 128 + og * 8];
            float4 a1 = *(const float4*)&A[r * 128 + og * 8 + 4];
            float4 bb = *(const float4*)&Bm[r * 64 + mg * 4];
            float av[8] = {a0.x,a0.y,a0.z,a0.w, a1.x,a1.y,a1.z,a1.w};
            float bv[4] = {bb.x, bb.y, bb.z, bb.w};
            #pragma unroll
            for (int oi = 0; oi < 8; ++oi)
                #pragma unroll
                for (int mi = 0; mi < 4; ++mi)
                    acc2[oi][mi] += av[oi] * bv[mi];
        }
    }
    #pragma unroll
    for (int oi = 0; oi < 8; ++oi) {
        int o = o0b + og * 8 + oi;
        float fb = fuse_b[o], gb = gate_b[o];
        #pragma unroll
        for (int mi = 0; mi < 4; ++mi) {
            int m = m0b + mg * 4 + mi;
            float f = acc1[oi][mi] + fb;
            float gl = acc2[oi][mi] + gb;
            float gt = 1.f / (1.f + __expf(-gl));
            float fg = feat_g[((size_t)b * CSEED + o) * MPT + m];
            out[((size_t)b * CSEED + o) * MPT + m] = f + gt * fg;
        }
    }
}

// ---------------------------------------------------------------- launcher
extern "C" void kernel_launch(void* const* d_in, const int* in_sizes, int n_in,
                              void* d_out, int out_size, void* d_ws, size_t ws_size,
                              hipStream_t stream) {
    const float* seed_xyz      = (const float*)d_in[0];
    const float* seed_features = (const float*)d_in[1];
    const void*  mask_raw      = d_in[2];
    const float* views_rot     = (const float*)d_in[3];
    const float* crop_w1       = (const float*)d_in[4];
    const float* crop_b1       = (const float*)d_in[5];
    const float* crop_w2       = (const float*)d_in[6];
    const float* crop_b2       = (const float*)d_in[7];
    const float* fuse_w        = (const float*)d_in[8];
    const float* fuse_b        = (const float*)d_in[9];
    const float* gate_w        = (const float*)d_in[10];
    const float* gate_b        = (const float*)d_in[11];
    float* out = (float*)d_out;

    char* ws = (char*)d_ws;
    size_t off = 0;
    auto alloc = [&](size_t bytes) -> void* {
        void* p = ws + off;
        off = (off + bytes + 255) & ~(size_t)255;
        return p;
    };
    int*    mode   = (int*)   alloc(16);
    int*    fpsidx = (int*)   alloc((size_t)B_SZ * MPT * 4);
    float4* cp     = (float4*)alloc((size_t)B_SZ * 15008 * 16);
    float*  xyzg   = (float*) alloc((size_t)B_SZ * MPT * 3 * 4);
    float*  featg  = (float*) alloc((size_t)B_SZ * CSEED * MPT * 4);
    float*  f1t    = (float*) alloc((size_t)4 * B_SZ * MPT * 256 * 4);
    int*    selidx = (int*)   alloc((size_t)4 * B_SZ * MPT * 64 * 4);
    float*  selxyz = (float*) alloc((size_t)4 * B_SZ * MPT * 64 * 3 * 4);
    float*  w2t    = (float*) alloc((size_t)4 * 256 * 512 * 4);
    float*  vpcat  = (float*) alloc((size_t)B_SZ * 4 * 512 * MPT * 4);

    k_detect<<<1, 256, 0, stream>>>((const unsigned int*)mask_raw, mode);
    k_fps<<<B_SZ, FPS_T, 0, stream>>>(mask_raw, mode, seed_xyz, cp, fpsidx);
    k_gather<<<B_SZ * CSEED + B_SZ, 256, 0, stream>>>(seed_features, seed_xyz, fpsidx, featg, xyzg);
    k_w2t<<<(4 * 512 * 256) / 256, 256, 0, stream>>>(crop_w2, w2t);
    k_f1<<<128, 256, 0, stream>>>(featg, crop_w1, crop_b1, f1t);
    k_select<<<(B_SZ * MPT) / 4, 256, 0, stream>>>(xyzg, views_rot, selidx, selxyz);
    const int NS[4] = {16, 32, 32, 64};
    const int L2NS[4] = {4, 5, 5, 6};
    for (int s = 0; s < 4; ++s) {
        int jt = 64 >> L2NS[s];
        k_crop<<<B_SZ * (MPT / jt), 256, 0, stream>>>(s, NS[s], L2NS[s],
            f1t, crop_w1, w2t, crop_b2, selidx, selxyz, vpcat);
    }
    k_out<<<128, 256, 0, stream>>>(vpcat, featg, fuse_w, fuse_b, gate_w, gate_b, out);
}

// Round 2
// 4081.681 us; speedup vs baseline: 1.0617x; 1.0617x over previous
//
#include <hip/hip_runtime.h>
#include <stdint.h>
#include <stddef.h>

#define B_SZ   2
#define N_PTS  15000
#define MPT    1024
#define CSEED  512
#define HMINF (-0.02f)
#define HMAXF (0.06f)

// ---------------------------------------------------------------- mask dtype detect
// mode 0: int32 {0,1}; mode 1: float32 {0.0,1.0}; mode 2: bytes
__global__ void k_detect(const unsigned int* mraw, int* mode_out) {
    __shared__ int vi, vf;
    if (threadIdx.x == 0) { vi = 0; vf = 0; }
    __syncthreads();
    int li = 0, lf = 0;
    for (int i = threadIdx.x; i < (B_SZ * N_PTS) / 4; i += blockDim.x) {
        unsigned int u = mraw[i];
        if (u != 0u && u != 1u) li = 1;
        if (u != 0u && u != 0x3F800000u) lf = 1;
    }
    if (li) atomicOr(&vi, 1);
    if (lf) atomicOr(&vf, 1);
    __syncthreads();
    if (threadIdx.x == 0) *mode_out = (vi == 0) ? 0 : ((vf == 0) ? 1 : 2);
}

// ---------------------------------------------------------------- masked FPS v2
// 512 threads/block, 1 block/batch. Points spatially sorted (8x8x8 counting
// sort) into contiguous per-thread register chunks; per-thread bbox prune
// (exact: skip only when dist(bbox,far)^2 >= max pd in chunk); 1 barrier/iter
// via parity-double-buffered 8-wave LDS publish + redundant all-thread scan.
#define FPS_T 512
#define FPS_K 30

__global__ __launch_bounds__(FPS_T) void k_fps(
        const void* mask_raw, const int* mode_p, const float* seed_xyz,
        float4* cp, int* fps_idx)
{
    const int b    = blockIdx.x;
    const int tid  = threadIdx.x;
    const int wv   = tid >> 6;
    const int lane = tid & 63;
    const int mode = *mode_p;

    __shared__ int s_cell[512];
    __shared__ int s_total, s_start;
    __shared__ float s_fx, s_fy, s_fz;
    __shared__ unsigned long long s_wkey[2][8];
    __shared__ float s_wx[2][8], s_wy[2][8], s_wz[2][8];

    if (tid == 0) s_start = 0x7fffffff;
    s_cell[tid] = 0;
    __syncthreads();

    auto rd_mask = [&](int i) -> bool {
        if (mode == 0) return ((const int*)mask_raw)[b * N_PTS + i] != 0;
        if (mode == 1) return ((const unsigned int*)mask_raw)[b * N_PTS + i] != 0u;
        return ((const unsigned char*)mask_raw)[b * N_PTS + i] != 0;
    };
    auto cell_of = [&](float x, float y, float z) -> int {
        int cx = (int)(x * 40.f); cx = cx < 0 ? 0 : (cx > 7 ? 7 : cx);
        int cy = (int)(y * 40.f); cy = cy < 0 ? 0 : (cy > 7 ? 7 : cy);
        int cz = (int)(z * 40.f); cz = cz < 0 ? 0 : (cz > 7 ? 7 : cz);
        return (cx << 6) | (cy << 3) | cz;
    };

    // pass 1: per-cell histogram + first masked index
    int myfirst = 0x7fffffff;
    for (int k = 0; k < FPS_K; ++k) {
        int i = tid + k * FPS_T;
        if (i < N_PTS && rd_mask(i)) {
            if (i < myfirst) myfirst = i;
            float x = seed_xyz[(size_t)(b * N_PTS + i) * 3 + 0];
            float y = seed_xyz[(size_t)(b * N_PTS + i) * 3 + 1];
            float z = seed_xyz[(size_t)(b * N_PTS + i) * 3 + 2];
            atomicAdd(&s_cell[cell_of(x, y, z)], 1);
        }
    }
    if (myfirst != 0x7fffffff) atomicMin(&s_start, myfirst);
    __syncthreads();
    if (tid == 0) {                                    // serial exclusive prefix (one-time)
        int run = 0;
        for (int i = 0; i < 512; ++i) { int t = s_cell[i]; s_cell[i] = run; run += t; }
        s_total = run;
    }
    __syncthreads();
    const int Mc = s_total;
    const int start = s_start;
    if (Mc == 0) {
        for (int m = tid; m < MPT; m += FPS_T) fps_idx[b * MPT + m] = 0;
        return;
    }

    // pass 2: scatter into spatially-sorted compact array (x,y,z,origidx)
    for (int k = 0; k < FPS_K; ++k) {
        int i = tid + k * FPS_T;
        if (i < N_PTS && rd_mask(i)) {
            float x = seed_xyz[(size_t)(b * N_PTS + i) * 3 + 0];
            float y = seed_xyz[(size_t)(b * N_PTS + i) * 3 + 1];
            float z = seed_xyz[(size_t)(b * N_PTS + i) * 3 + 2];
            int pos = atomicAdd(&s_cell[cell_of(x, y, z)], 1);
            cp[b * 15008 + pos] = make_float4(x, y, z, __int_as_float(i));
        }
    }
    __threadfence_block();
    __syncthreads();

    // load contiguous chunk into registers + per-thread bbox
    const int L = (Mc + FPS_T - 1) / FPS_T;            // uniform across block
    float px[FPS_K], py[FPS_K], pz[FPS_K], pd[FPS_K];
    int pid[FPS_K];
    float bbnx = 1e30f, bbny = 1e30f, bbnz = 1e30f;
    float bbxx = -1e30f, bbxy = -1e30f, bbxz = -1e30f;
    int nact = 0;
    #pragma unroll
    for (int k = 0; k < FPS_K; ++k) {
        if (k < L) {
            int c = tid * L + k;
            if (c < Mc) {
                float4 v = cp[b * 15008 + c];
                px[k] = v.x; py[k] = v.y; pz[k] = v.z;
                pid[k] = __float_as_int(v.w);
                pd[k] = 1e10f;
                bbnx = fminf(bbnx, v.x); bbny = fminf(bbny, v.y); bbnz = fminf(bbnz, v.z);
                bbxx = fmaxf(bbxx, v.x); bbxy = fmaxf(bbxy, v.y); bbxz = fmaxf(bbxz, v.z);
                nact++;
            } else { px[k] = 0.f; py[k] = 0.f; pz[k] = 0.f; pid[k] = -1; pd[k] = -1.f; }
        } else { px[k] = 0.f; py[k] = 0.f; pz[k] = 0.f; pid[k] = -1; pd[k] = -1.f; }
    }

    // publish start point's coords (unique owner)
    #pragma unroll
    for (int k = 0; k < FPS_K; ++k)
        if (k < L && pid[k] == start) { s_fx = px[k]; s_fy = py[k]; s_fz = pz[k]; }
    __syncthreads();

    float fx = s_fx, fy = s_fy, fz = s_fz;
    int widx = start;
    // cached per-thread best: bval = max pd in chunk (valid after first iter;
    // init 1e10 guarantees first iter is never pruned), (bidx,bx,by,bz) = winner
    float bval = (nact > 0) ? 1e10f : -0.5f;
    int bidx = 0;
    float bx = 0.f, by = 0.f, bz = 0.f;
    int par = 0;

    for (int m = 0; m < MPT; ++m) {
        if (tid == 0) fps_idx[b * MPT + m] = widx;     // sel[m] = far (before update)

        // exact prune: if min dist from bbox to far >= max pd, no pd can change
        float ex = fmaxf(fmaxf(bbnx - fx, fx - bbxx), 0.f);
        float ey = fmaxf(fmaxf(bbny - fy, fy - bbxy), 0.f);
        float ez = fmaxf(fmaxf(bbnz - fz, fz - bbxz), 0.f);
        float dmin2 = ex * ex + ey * ey + ez * ez;
        if (dmin2 < bval) {
            float nv = -0.5f; int ni = 0; float nx = 0.f, ny = 0.f, nz = 0.f;
            #pragma unroll
            for (int k = 0; k < FPS_K; ++k) {
                if (k < L) {
                    // exact np op order: sub/mul then ((d0+d1)+d2), no fma contraction
                    float dx = __fsub_rn(px[k], fx);
                    float dy = __fsub_rn(py[k], fy);
                    float dz = __fsub_rn(pz[k], fz);
                    float d  = __fadd_rn(__fadd_rn(__fmul_rn(dx, dx), __fmul_rn(dy, dy)),
                                         __fmul_rn(dz, dz));
                    float nd = fminf(pd[k], d);
                    pd[k] = nd;
                    bool better = (nd > nv) || (nd == nv && pid[k] < ni);
                    if (better) { nv = nd; ni = pid[k]; nx = px[k]; ny = py[k]; nz = pz[k]; }
                }
            }
            bval = nv; bidx = ni; bx = nx; by = ny; bz = nz;
        }

        // 64-lane reduce: key = (bits(val)<<32) | ~idx  (max => np.argmax tie-break)
        unsigned long long key = (bval >= 0.f)
            ? ((((unsigned long long)__float_as_uint(bval)) << 32)
               | (unsigned long long)(unsigned int)(~(unsigned int)bidx))
            : 0ull;
        float rx = bx, ry = by, rz = bz;
        #pragma unroll
        for (int s = 1; s < 64; s <<= 1) {
            unsigned long long ok = __shfl_xor(key, s, 64);
            float ox = __shfl_xor(rx, s, 64);
            float oy = __shfl_xor(ry, s, 64);
            float oz = __shfl_xor(rz, s, 64);
            if (ok > key) { key = ok; rx = ox; ry = oy; rz = oz; }
        }
        if (lane == 0) {
            s_wkey[par][wv] = key;
            s_wx[par][wv] = rx; s_wy[par][wv] = ry; s_wz[par][wv] = rz;
        }
        __syncthreads();
        // redundant all-thread scan of 8 wave results (LDS broadcast reads)
        unsigned long long bk = s_wkey[par][0]; int bw = 0;
        #pragma unroll
        for (int w = 1; w < 8; ++w) {
            unsigned long long o = s_wkey[par][w];
            if (o > bk) { bk = o; bw = w; }
        }
        fx = s_wx[par][bw]; fy = s_wy[par][bw]; fz = s_wz[par][bw];
        widx = (int)(~(unsigned int)(bk & 0xffffffffull));
        par ^= 1;
    }
}

// ---------------------------------------------------------------- gathers
__global__ void k_gather(const float* seed_features, const float* seed_xyz,
                         const int* fps_idx, float* feat_g, float* xyz_g)
{
    int e = blockIdx.x;
    if (e < B_SZ * CSEED) {
        int b = e >> 9, c = e & (CSEED - 1);
        const float* src = seed_features + (size_t)(b * CSEED + c) * N_PTS;
        float* dst = feat_g + (size_t)(b * CSEED + c) * MPT;
        const int* idx = fps_idx + b * MPT;
        for (int m = threadIdx.x; m < MPT; m += blockDim.x) dst[m] = src[idx[m]];
    } else {
        int b = e - B_SZ * CSEED;
        const int* idx = fps_idx + b * MPT;
        for (int m = threadIdx.x; m < MPT; m += blockDim.x) {
            int p = idx[m];
            xyz_g[(size_t)(b * MPT + m) * 3 + 0] = seed_xyz[(size_t)(b * N_PTS + p) * 3 + 0];
            xyz_g[(size_t)(b * MPT + m) * 3 + 1] = seed_xyz[(size_t)(b * N_PTS + p) * 3 + 1];
            xyz_g[(size_t)(b * MPT + m) * 3 + 2] = seed_xyz[(size_t)(b * N_PTS + p) * 3 + 2];
        }
    }
}

// ---------------------------------------------------------------- W2 transpose: w2t[s][c][o]
__global__ void k_w2t(const float* crop_w2, float* w2t) {
    int i = blockIdx.x * blockDim.x + threadIdx.x;
    if (i >= 4 * 512 * 256) return;
    int s = i >> 17;
    int r = i & 131071;
    int c = r >> 9, o = r & 511;
    w2t[i] = crop_w2[(size_t)(s * 512 + o) * 256 + c];
}

// ---------------------------------------------------------------- F1T = feat_g^T * W1f^T + b1
__global__ __launch_bounds__(256) void k_f1(const float* feat_g, const float* crop_w1,
                                            const float* crop_b1, float* f1t)
{
    const int blk = blockIdx.x;
    const int pt = blk & 15;
    const int b  = (blk >> 4) & 1;
    const int s  = blk >> 5;
    const int p0 = pt * 64;
    __shared__ float A[16][64];
    __shared__ float Bm[16][256];
    const int tid = threadIdx.x;
    const int pg = tid & 15, og = tid >> 4;
    float acc[4][16];
    #pragma unroll
    for (int i = 0; i < 4; ++i)
        #pragma unroll
        for (int j = 0; j < 16; ++j) acc[i][j] = 0.f;

    for (int kc = 0; kc < CSEED; kc += 16) {
        __syncthreads();
        {
            int r = tid >> 4, pp = (tid & 15) * 4;
            *(float4*)&A[r][pp] =
                *(const float4*)&feat_g[(size_t)(b * CSEED + kc + r) * MPT + p0 + pp];
            #pragma unroll
            for (int r2 = 0; r2 < 16; ++r2)
                Bm[r2][tid] = crop_w1[(size_t)(s * 256 + tid) * 515 + 3 + kc + r2];
        }
        __syncthreads();
        #pragma unroll
        for (int r = 0; r < 16; ++r) {
            float4 a4 = *(const float4*)&A[r][pg * 4];
            float av[4] = {a4.x, a4.y, a4.z, a4.w};
            float bv[16];
            #pragma unroll
            for (int q = 0; q < 4; ++q) {
                float4 b4 = *(const float4*)&Bm[r][og * 16 + q * 4];
                bv[q*4+0] = b4.x; bv[q*4+1] = b4.y; bv[q*4+2] = b4.z; bv[q*4+3] = b4.w;
            }
            #pragma unroll
            for (int i = 0; i < 4; ++i)
                #pragma unroll
                for (int j = 0; j < 16; ++j)
                    acc[i][j] += av[i] * bv[j];
        }
    }
    #pragma unroll
    for (int i = 0; i < 4; ++i) {
        size_t row = (size_t)((s * B_SZ + b) * MPT + p0 + pg * 4 + i) * 256;
        #pragma unroll
        for (int q = 0; q < 4; ++q) {
            float4 o4;
            o4.x = acc[i][q*4+0] + crop_b1[s*256 + og*16 + q*4+0];
            o4.y = acc[i][q*4+1] + crop_b1[s*256 + og*16 + q*4+1];
            o4.z = acc[i][q*4+2] + crop_b1[s*256 + og*16 + q*4+2];
            o4.w = acc[i][q*4+3] + crop_b1[s*256 + og*16 + q*4+3];
            *(float4*)&f1t[row + og * 16 + q * 4] = o4;
        }
    }
}

// ---------------------------------------------------------------- local coords + neighbor select
__global__ __launch_bounds__(256) void k_select(const float* xyz_g, const float* views_rot,
                                                int* sel_idx, float* sel_xyz)
{
    const int wv = threadIdx.x >> 6;
    const int lane = threadIdx.x & 63;
    const int gj = blockIdx.x * 4 + wv;
    const int b = gj >> 10, j = gj & (MPT - 1);

    const float cx = xyz_g[(size_t)(b * MPT + j) * 3 + 0];
    const float cy = xyz_g[(size_t)(b * MPT + j) * 3 + 1];
    const float cz = xyz_g[(size_t)(b * MPT + j) * 3 + 2];
    const float* R = views_rot + (size_t)(b * MPT + j) * 9;
    const float r00 = R[0], r01 = R[1], r02 = R[2];
    const float r10 = R[3], r11 = R[4], r12 = R[5];
    const float r20 = R[6], r21 = R[7], r22 = R[8];

    const float R2C[4] = { (float)(0.025 * 0.025), (float)(0.0375 * 0.0375),
                           (float)(0.05 * 0.05),   (float)(0.075 * 0.075) };
    const int NSs[4] = {16, 32, 32, 64};

    __shared__ float s_zloc[4][3];
    __shared__ int   s_padk[4][4];
    __shared__ float s_padx[4][4][3];

    int cnt[4] = {0, 0, 0, 0};

    for (int ch = 0; ch < 16; ++ch) {
        int k = ch * 64 + lane;
        float x = xyz_g[(size_t)(b * MPT + k) * 3 + 0];
        float y = xyz_g[(size_t)(b * MPT + k) * 3 + 1];
        float z = xyz_g[(size_t)(b * MPT + k) * 3 + 2];
        float rx = __fsub_rn(x, cx), ry = __fsub_rn(y, cy), rz = __fsub_rn(z, cz);
        float l0 = __fadd_rn(__fadd_rn(__fmul_rn(rx, r00), __fmul_rn(ry, r10)), __fmul_rn(rz, r20));
        float l1 = __fadd_rn(__fadd_rn(__fmul_rn(rx, r01), __fmul_rn(ry, r11)), __fmul_rn(rz, r21));
        float l2 = __fadd_rn(__fadd_rn(__fmul_rn(rx, r02), __fmul_rn(ry, r12)), __fmul_rn(rz, r22));
        float r2 = __fadd_rn(__fmul_rn(l1, l1), __fmul_rn(l2, l2));
        bool inh = (l0 >= HMINF) && (l0 <= HMAXF);
        if (ch == 0 && lane == 0) { s_zloc[wv][0] = l0; s_zloc[wv][1] = l1; s_zloc[wv][2] = l2; }
        #pragma unroll
        for (int sc = 0; sc < 4; ++sc) {
            bool v = inh && (r2 < R2C[sc]);
            unsigned long long bal = __ballot(v);
            int pre = __popcll(bal & ((1ull << lane) - 1ull));
            int p = cnt[sc] + pre;
            if (v && p < NSs[sc]) {
                size_t sb = ((size_t)(sc * B_SZ + b) * MPT + j) * 64 + p;
                sel_idx[sb] = k;
                sel_xyz[sb * 3 + 0] = l0;
                sel_xyz[sb * 3 + 1] = l1;
                sel_xyz[sb * 3 + 2] = l2;
                if (p == 0) {
                    s_padk[wv][sc] = k;
                    s_padx[wv][sc][0] = l0; s_padx[wv][sc][1] = l1; s_padx[wv][sc][2] = l2;
                }
            }
            cnt[sc] += __popcll(bal);
        }
    }
    __syncthreads();
    #pragma unroll
    for (int sc = 0; sc < 4; ++sc) {
        int cs = cnt[sc];
        int pk; float a0, a1, a2;
        if (cs > 0) { pk = s_padk[wv][sc]; a0 = s_padx[wv][sc][0]; a1 = s_padx[wv][sc][1]; a2 = s_padx[wv][sc][2]; }
        else        { pk = 0; a0 = s_zloc[wv][0]; a1 = s_zloc[wv][1]; a2 = s_zloc[wv][2]; }
        for (int n = cs + lane; n < NSs[sc]; n += 64) {
            size_t sb = ((size_t)(sc * B_SZ + b) * MPT + j) * 64 + n;
            sel_idx[sb] = pk;
            sel_xyz[sb * 3 + 0] = a0; sel_xyz[sb * 3 + 1] = a1; sel_xyz[sb * 3 + 2] = a2;
        }
    }
}

// ---------------------------------------------------------------- crop MLP: h1 assemble + GEMM2 + maxpool
__global__ __launch_bounds__(256) void k_crop(
        const int s, const int ns, const int log2ns,
        const float* f1t, const float* crop_w1, const float* w2t, const float* crop_b2,
        const int* sel_idx, const float* sel_xyz, float* vp_cat)
{
    const int tid = threadIdx.x;
    const int jt = 64 >> log2ns;
    const int nj = MPT / jt;
    const int b = blockIdx.x / nj;
    const int jbase = (blockIdx.x % nj) * jt;

    __shared__ float h1[128 * 64];
    __shared__ float w2c[8 * 512];
    __shared__ float w1xa[3 * 256];

    for (int i = tid; i < 768; i += 256) {
        int a = i >> 8, o = i & 255;
        w1xa[i] = crop_w1[(size_t)(s * 256 + o) * 515 + a];
    }

    const int col = tid & 63;
    const int cq = tid >> 6;
    const int jl = col >> log2ns;
    const int nn = col & (ns - 1);
    const size_t sb = ((size_t)(s * B_SZ + b) * MPT + jbase + jl) * 64 + nn;
    const int p = sel_idx[sb];
    const float gx = sel_xyz[sb * 3 + 0];
    const float gy = sel_xyz[sb * 3 + 1];
    const float gz = sel_xyz[sb * 3 + 2];
    const float* f1row = f1t + (size_t)((s * B_SZ + b) * MPT + p) * 256;

    const int ogrp = tid >> 3;
    const int cgrp = tid & 7;
    const int o0 = ogrp * 16, col0 = cgrp * 8;
    const float* w2s = w2t + (size_t)s * 256 * 512;

    float acc[16][8];
    #pragma unroll
    for (int i = 0; i < 16; ++i)
        #pragma unroll
        for (int jq = 0; jq < 8; ++jq) acc[i][jq] = 0.f;

    for (int half = 0; half < 2; ++half) {
        __syncthreads();
        #pragma unroll
        for (int cg4 = 0; cg4 < 8; ++cg4) {
            int cpr = cq * 32 + cg4 * 4;
            int c = half * 128 + cpr;
            float4 fv = *(const float4*)&f1row[c];
            float vv[4] = {fv.x, fv.y, fv.z, fv.w};
            #pragma unroll
            for (int q = 0; q < 4; ++q) {
                int c2 = c + q;
                float v = vv[q] + w1xa[c2] * gx + w1xa[256 + c2] * gy + w1xa[512 + c2] * gz;
                h1[(cpr + q) * 64 + col] = fmaxf(v, 0.f);
            }
        }
        __syncthreads();
        for (int cc = 0; cc < 16; ++cc) {
            __syncthreads();
            #pragma unroll
            for (int i = 0; i < 4; ++i) {
                int e = tid + i * 256;
                int r = e >> 7, o4 = (e & 127) * 4;
                *(float4*)&w2c[r * 512 + o4] =
                    *(const float4*)&w2s[(size_t)(half * 128 + cc * 8 + r) * 512 + o4];
            }
            __syncthreads();
            #pragma unroll
            for (int c8 = 0; c8 < 8; ++c8) {
                const float* hp = &h1[(cc * 8 + c8) * 64 + col0];
                float4 b0 = *(const float4*)hp;
                float4 b1 = *(const float4*)(hp + 4);
                const float* ap = &w2c[c8 * 512 + o0];
                float4 a0 = *(const float4*)ap;
                float4 a1 = *(const float4*)(ap + 4);
                float4 a2 = *(const float4*)(ap + 8);
                float4 a3 = *(const float4*)(ap + 12);
                float av[16] = {a0.x,a0.y,a0.z,a0.w, a1.x,a1.y,a1.z,a1.w,
                                a2.x,a2.y,a2.z,a2.w, a3.x,a3.y,a3.z,a3.w};
                float bv[8]  = {b0.x,b0.y,b0.z,b0.w, b1.x,b1.y,b1.z,b1.w};
                #pragma unroll
                for (int oi = 0; oi < 16; ++oi)
                    #pragma unroll
                    for (int ci = 0; ci < 8; ++ci)
                        acc[oi][ci] += av[oi] * bv[ci];
            }
        }
    }
    __syncthreads();
    float* mbuf = w2c;
    #pragma unroll
    for (int oi = 0; oi < 16; ++oi) {
        float mx = acc[oi][0];
        #pragma unroll
        for (int ci = 1; ci < 8; ++ci) mx = fmaxf(mx, acc[oi][ci]);
        mbuf[(o0 + oi) * 8 + cgrp] = mx;
    }
    __syncthreads();
    const int g = ns >> 3;
    for (int t = tid; t < 512 * jt; t += 256) {
        int o = t & 511, jl2 = t >> 9;
        float v = mbuf[o * 8 + jl2 * g];
        for (int q = 1; q < g; ++q) v = fmaxf(v, mbuf[o * 8 + jl2 * g + q]);
        v = fmaxf(v + crop_b2[s * 512 + o], 0.f);
        vp_cat[((size_t)(b * 4 + s) * 512 + o) * MPT + jbase + jl2] = v;
    }
}

// ---------------------------------------------------------------- fuse + gate + output
__global__ __launch_bounds__(256) void k_out(
        const float* vp_cat, const float* feat_g,
        const float* fuse_w, const float* fuse_b,
        const float* gate_w, const float* gate_b, float* out)
{
    const int blk = blockIdx.x;
    const int mt = blk & 15, ot = (blk >> 4) & 3, b = blk >> 6;
    const int o0b = ot * 128, m0b = mt * 64;
    __shared__ float A[16 * 128];
    __shared__ float Bm[16 * 64];
    const int tid = threadIdx.x;
    const int og = tid >> 4, mg = tid & 15;
    float acc1[8][4], acc2[8][4];
    #pragma unroll
    for (int i = 0; i < 8; ++i)
        #pragma unroll
        for (int jq = 0; jq < 4; ++jq) { acc1[i][jq] = 0.f; acc2[i][jq] = 0.f; }

    for (int kc = 0; kc < 2048; kc += 16) {
        __syncthreads();
        {
            int oo = tid >> 1, r0 = (tid & 1) * 8;
            const float* srow = fuse_w + (size_t)(o0b + oo) * 2048 + kc + r0;
            float4 u0 = *(const float4*)srow;
            float4 u1 = *(const float4*)(srow + 4);
            A[(r0 + 0) * 128 + oo] = u0.x; A[(r0 + 1) * 128 + oo] = u0.y;
            A[(r0 + 2) * 128 + oo] = u0.z; A[(r0 + 3) * 128 + oo] = u0.w;
            A[(r0 + 4) * 128 + oo] = u1.x; A[(r0 + 5) * 128 + oo] = u1.y;
            A[(r0 + 6) * 128 + oo] = u1.z; A[(r0 + 7) * 128 + oo] = u1.w;
            int r = tid >> 4, mm = (tid & 15) * 4;
            *(float4*)&Bm[r * 64 + mm] =
                *(const float4*)&vp_cat[((size_t)b * 2048 + kc + r) * MPT + m0b + mm];
        }
        __syncthreads();
        #pragma unroll
        for (int r = 0; r < 16; ++r) {
            float4 a0 = *(const float4*)&A[r * 128 + og * 8];
            float4 a1 = *(const float4*)&A[r * 128 + og * 8 + 4];
            float4 bb = *(const float4*)&Bm[r * 64 + mg * 4];
            float av[8] = {a0.x,a0.y,a0.z,a0.w, a1.x,a1.y,a1.z,a1.w};
            float bv[4] = {bb.x, bb.y, bb.z, bb.w};
            #pragma unroll
            for (int oi = 0; oi < 8; ++oi)
                #pragma unroll
                for (int mi = 0; mi < 4; ++mi)
                    acc1[oi][mi] += av[oi] * bv[mi];
        }
    }
    for (int kc = 0; kc < 512; kc += 16) {
        __syncthreads();
        {
            int oo = tid >> 1, r0 = (tid & 1) * 8;
            const float* srow = gate_w + (size_t)(o0b + oo) * 512 + kc + r0;
            float4 u0 = *(const float4*)srow;
            float4 u1 = *(const float4*)(srow + 4);
            A[(r0 + 0) * 128 + oo] = u0.x; A[(r0 + 1) * 128 + oo] = u0.y;
            A[(r0 + 2) * 128 + oo] = u0.z; A[(r0 + 3) * 128 + oo] = u0.w;
            A[(r0 + 4) * 128 + oo] = u1.x; A[(r0 + 5) * 128 + oo] = u1.y;
            A[(r0 + 6) * 128 + oo] = u1.z; A[(r0 + 7) * 128 + oo] = u1.w;
            int r = tid >> 4, mm = (tid & 15) * 4;
            *(float4*)&Bm[r * 64 + mm] =
                *(const float4*)&feat_g[((size_t)b * CSEED + kc + r) * MPT + m0b + mm];
        }
        __syncthreads();
        #pragma unroll
        for (int r = 0; r < 16; ++r) {
            float4 a0 = *(const float4*)&A[r * 128 + og * 8];
            float4 a1 = *(const float4*)&A[r * 128 + og * 8 + 4];
            float4 bb = *(const float4*)&Bm[r * 64 + mg * 4];
            float av[8] = {a0.x,a0.y,a0.z,a0.w, a1.x,a1.y,a1.z,a1.w};
            float bv[4] = {bb.x, bb.y, bb.z, bb.w};
            #pragma unroll
            for (int oi = 0; oi < 8; ++oi)
                #pragma unroll
                for (int mi = 0; mi < 4; ++mi)
                    acc2[oi][mi] += av[oi] * bv[mi];
        }
    }
    #pragma unroll
    for (int oi = 0; oi < 8; ++oi) {
        int o = o0b + og * 8 + oi;
        float fb = fuse_b[o], gb = gate_b[o];
        #pragma unroll
        for (int mi = 0; mi < 4; ++mi) {
            int m = m0b + mg * 4 + mi;
            float f = acc1[oi][mi] + fb;
            float gl = acc2[oi][mi] + gb;
            float gt = 1.f / (1.f + __expf(-gl));
            float fg = feat_g[((size_t)b * CSEED + o) * MPT + m];
            out[((size_t)b * CSEED + o) * MPT + m] = f + gt * fg;
        }
    }
}

// ---------------------------------------------------------------- launcher
extern "C" void kernel_launch(void* const* d_in, const int* in_sizes, int n_in,
                              void* d_out, int out_size, void* d_ws, size_t ws_size,
                              hipStream_t stream) {
    const float* seed_xyz      = (const float*)d_in[0];
    const float* seed_features = (const float*)d_in[1];
    const void*  mask_raw      = d_in[2];
    const float* views_rot     = (const float*)d_in[3];
    const float* crop_w1       = (const float*)d_in[4];
    const float* crop_b1       = (const float*)d_in[5];
    const float* crop_w2       = (const float*)d_in[6];
    const float* crop_b2       = (const float*)d_in[7];
    const float* fuse_w        = (const float*)d_in[8];
    const float* fuse_b        = (const float*)d_in[9];
    const float* gate_w        = (const float*)d_in[10];
    const float* gate_b        = (const float*)d_in[11];
    float* out = (float*)d_out;

    char* ws = (char*)d_ws;
    size_t off = 0;
    auto alloc = [&](size_t bytes) -> void* {
        void* p = ws + off;
        off = (off + bytes + 255) & ~(size_t)255;
        return p;
    };
    int*    mode   = (int*)   alloc(16);
    int*    fpsidx = (int*)   alloc((size_t)B_SZ * MPT * 4);
    float4* cp     = (float4*)alloc((size_t)B_SZ * 15008 * 16);
    float*  xyzg   = (float*) alloc((size_t)B_SZ * MPT * 3 * 4);
    float*  featg  = (float*) alloc((size_t)B_SZ * CSEED * MPT * 4);
    float*  f1t    = (float*) alloc((size_t)4 * B_SZ * MPT * 256 * 4);
    int*    selidx = (int*)   alloc((size_t)4 * B_SZ * MPT * 64 * 4);
    float*  selxyz = (float*) alloc((size_t)4 * B_SZ * MPT * 64 * 3 * 4);
    float*  w2t    = (float*) alloc((size_t)4 * 256 * 512 * 4);
    float*  vpcat  = (float*) alloc((size_t)B_SZ * 4 * 512 * MPT * 4);

    k_detect<<<1, 256, 0, stream>>>((const unsigned int*)mask_raw, mode);
    k_fps<<<B_SZ, FPS_T, 0, stream>>>(mask_raw, mode, seed_xyz, cp, fpsidx);
    k_gather<<<B_SZ * CSEED + B_SZ, 256, 0, stream>>>(seed_features, seed_xyz, fpsidx, featg, xyzg);
    k_w2t<<<(4 * 512 * 256) / 256, 256, 0, stream>>>(crop_w2, w2t);
    k_f1<<<128, 256, 0, stream>>>(featg, crop_w1, crop_b1, f1t);
    k_select<<<(B_SZ * MPT) / 4, 256, 0, stream>>>(xyzg, views_rot, selidx, selxyz);
    const int NS[4] = {16, 32, 32, 64};
    const int L2NS[4] = {4, 5, 5, 6};
    for (int s = 0; s < 4; ++s) {
        int jt = 64 >> L2NS[s];
        k_crop<<<B_SZ * (MPT / jt), 256, 0, stream>>>(s, NS[s], L2NS[s],
            f1t, crop_w1, w2t, crop_b2, selidx, selxyz, vpcat);
    }
    k_out<<<128, 256, 0, stream>>>(vpcat, featg, fuse_w, fuse_b, gate_w, gate_b, out);
}

// Round 3
// 2979.947 us; speedup vs baseline: 1.4542x; 1.3697x over previous
//
#include <hip/hip_runtime.h>
#include <stdint.h>
#include <stddef.h>

#define B_SZ   2
#define N_PTS  15000
#define MPT    1024
#define CSEED  512
#define HMINF (-0.02f)
#define HMAXF (0.06f)

typedef __attribute__((ext_vector_type(8))) short bf16x8;
typedef __attribute__((ext_vector_type(4))) float f32x4;

__device__ inline unsigned short f2bf(float f) {
    unsigned u = __float_as_uint(f);
    unsigned r = (u + 0x7fffu + ((u >> 16) & 1u)) >> 16;   // RNE, finite inputs
    return (unsigned short)r;
}

// ---------------------------------------------------------------- mask dtype detect
__global__ void k_detect(const unsigned int* mraw, int* mode_out) {
    __shared__ int vi, vf;
    if (threadIdx.x == 0) { vi = 0; vf = 0; }
    __syncthreads();
    int li = 0, lf = 0;
    for (int i = threadIdx.x; i < (B_SZ * N_PTS) / 4; i += blockDim.x) {
        unsigned int u = mraw[i];
        if (u != 0u && u != 1u) li = 1;
        if (u != 0u && u != 0x3F800000u) lf = 1;
    }
    if (li) atomicOr(&vi, 1);
    if (lf) atomicOr(&vf, 1);
    __syncthreads();
    if (threadIdx.x == 0) *mode_out = (vi == 0) ? 0 : ((vf == 0) ? 1 : 2);
}

// ---------------------------------------------------------------- masked FPS v3
// DPP wave argmax + readlane broadcast; Morton-sorted chunks; wave-uniform
// bbox prune with cached wave candidate; fps_idx in LDS; 1 barrier/iter.
#define FPS_T 512
#define FPS_K 30

__device__ inline unsigned dpp_max_u32(unsigned v) {   // valid in lane 63
    unsigned t;
    t = (unsigned)__builtin_amdgcn_update_dpp(0, (int)v, 0x111, 0xf, 0xf, false); v = v > t ? v : t;
    t = (unsigned)__builtin_amdgcn_update_dpp(0, (int)v, 0x112, 0xf, 0xf, false); v = v > t ? v : t;
    t = (unsigned)__builtin_amdgcn_update_dpp(0, (int)v, 0x114, 0xf, 0xf, false); v = v > t ? v : t;
    t = (unsigned)__builtin_amdgcn_update_dpp(0, (int)v, 0x118, 0xf, 0xf, false); v = v > t ? v : t;
    t = (unsigned)__builtin_amdgcn_update_dpp(0, (int)v, 0x142, 0xf, 0xf, false); v = v > t ? v : t;
    t = (unsigned)__builtin_amdgcn_update_dpp(0, (int)v, 0x143, 0xf, 0xf, false); v = v > t ? v : t;
    return v;
}
__device__ inline int dpp_min_i32(int v) {             // valid in lane 63
    int t;
    t = __builtin_amdgcn_update_dpp(0x7fffffff, v, 0x111, 0xf, 0xf, false); v = v < t ? v : t;
    t = __builtin_amdgcn_update_dpp(0x7fffffff, v, 0x112, 0xf, 0xf, false); v = v < t ? v : t;
    t = __builtin_amdgcn_update_dpp(0x7fffffff, v, 0x114, 0xf, 0xf, false); v = v < t ? v : t;
    t = __builtin_amdgcn_update_dpp(0x7fffffff, v, 0x118, 0xf, 0xf, false); v = v < t ? v : t;
    t = __builtin_amdgcn_update_dpp(0x7fffffff, v, 0x142, 0xf, 0xf, false); v = v < t ? v : t;
    t = __builtin_amdgcn_update_dpp(0x7fffffff, v, 0x143, 0xf, 0xf, false); v = v < t ? v : t;
    return v;
}

__global__ __launch_bounds__(FPS_T) void k_fps(
        const void* mask_raw, const int* mode_p, const float* seed_xyz,
        float4* cp, int* fps_idx)
{
    const int b    = blockIdx.x;
    const int tid  = threadIdx.x;
    const int wv   = tid >> 6;
    const int lane = tid & 63;
    const int mode = *mode_p;

    __shared__ int s_cell[512];
    __shared__ int s_total, s_start;
    __shared__ float s_fx, s_fy, s_fz;
    __shared__ unsigned long long s_wkey[2][8];
    __shared__ float s_wc[2][8][3];
    __shared__ int s_sel[MPT];

    if (tid == 0) s_start = 0x7fffffff;
    s_cell[tid] = 0;
    __syncthreads();

    auto rd_mask = [&](int i) -> bool {
        if (mode == 0) return ((const int*)mask_raw)[b * N_PTS + i] != 0;
        if (mode == 1) return ((const unsigned int*)mask_raw)[b * N_PTS + i] != 0u;
        return ((const unsigned char*)mask_raw)[b * N_PTS + i] != 0;
    };
    auto cell_of = [&](float x, float y, float z) -> int {  // Morton 8x8x8
        int cx = (int)(x * 40.f); cx = cx < 0 ? 0 : (cx > 7 ? 7 : cx);
        int cy = (int)(y * 40.f); cy = cy < 0 ? 0 : (cy > 7 ? 7 : cy);
        int cz = (int)(z * 40.f); cz = cz < 0 ? 0 : (cz > 7 ? 7 : cz);
        int m = 0;
        #pragma unroll
        for (int q = 0; q < 3; ++q)
            m |= (((cx >> q) & 1) << (3*q+2)) | (((cy >> q) & 1) << (3*q+1)) | (((cz >> q) & 1) << (3*q));
        return m;
    };

    // pass 1: histogram + first masked index
    int myfirst = 0x7fffffff;
    for (int k = 0; k < FPS_K; ++k) {
        int i = tid + k * FPS_T;
        if (i < N_PTS && rd_mask(i)) {
            if (i < myfirst) myfirst = i;
            float x = seed_xyz[(size_t)(b * N_PTS + i) * 3 + 0];
            float y = seed_xyz[(size_t)(b * N_PTS + i) * 3 + 1];
            float z = seed_xyz[(size_t)(b * N_PTS + i) * 3 + 2];
            atomicAdd(&s_cell[cell_of(x, y, z)], 1);
        }
    }
    if (myfirst != 0x7fffffff) atomicMin(&s_start, myfirst);
    __syncthreads();
    if (tid == 0) {
        int run = 0;
        for (int i = 0; i < 512; ++i) { int t = s_cell[i]; s_cell[i] = run; run += t; }
        s_total = run;
    }
    __syncthreads();
    const int Mc = s_total;
    const int start = s_start;
    if (Mc == 0) {
        for (int m = tid; m < MPT; m += FPS_T) fps_idx[b * MPT + m] = 0;
        return;
    }

    // pass 2: scatter into Morton-sorted compact array
    for (int k = 0; k < FPS_K; ++k) {
        int i = tid + k * FPS_T;
        if (i < N_PTS && rd_mask(i)) {
            float x = seed_xyz[(size_t)(b * N_PTS + i) * 3 + 0];
            float y = seed_xyz[(size_t)(b * N_PTS + i) * 3 + 1];
            float z = seed_xyz[(size_t)(b * N_PTS + i) * 3 + 2];
            int pos = atomicAdd(&s_cell[cell_of(x, y, z)], 1);
            cp[b * 15008 + pos] = make_float4(x, y, z, __int_as_float(i));
        }
    }
    __threadfence_block();
    __syncthreads();

    // load contiguous chunk + thread bbox
    const int L = (Mc + FPS_T - 1) / FPS_T;
    float px[FPS_K], py[FPS_K], pz[FPS_K], pd[FPS_K];
    int pid[FPS_K];
    float tnx = 1e30f, tny = 1e30f, tnz = 1e30f;
    float txx = -1e30f, txy = -1e30f, txz = -1e30f;
    #pragma unroll
    for (int k = 0; k < FPS_K; ++k) {
        bool ok = false;
        if (k < L) {
            int c = tid * L + k;
            if (c < Mc) {
                float4 v = cp[b * 15008 + c];
                px[k] = v.x; py[k] = v.y; pz[k] = v.z;
                pid[k] = __float_as_int(v.w);
                pd[k] = 1e10f;
                tnx = fminf(tnx, v.x); tny = fminf(tny, v.y); tnz = fminf(tnz, v.z);
                txx = fmaxf(txx, v.x); txy = fmaxf(txy, v.y); txz = fmaxf(txz, v.z);
                ok = true;
            }
        }
        if (!ok) { px[k] = 0.f; py[k] = 0.f; pz[k] = 0.f; pid[k] = 0x7fffffff; pd[k] = -1.f; }
    }
    // wave bbox (one-time shuffle reduce)
    #pragma unroll
    for (int s = 1; s < 64; s <<= 1) {
        tnx = fminf(tnx, __shfl_xor(tnx, s, 64));
        tny = fminf(tny, __shfl_xor(tny, s, 64));
        tnz = fminf(tnz, __shfl_xor(tnz, s, 64));
        txx = fmaxf(txx, __shfl_xor(txx, s, 64));
        txy = fmaxf(txy, __shfl_xor(txy, s, 64));
        txz = fmaxf(txz, __shfl_xor(txz, s, 64));
    }

    // publish start coords (unique owner)
    #pragma unroll
    for (int k = 0; k < FPS_K; ++k)
        if (k < L && pid[k] == start) { s_fx = px[k]; s_fy = py[k]; s_fz = pz[k]; }
    __syncthreads();

    float fx = s_fx, fy = s_fy, fz = s_fz;
    int widx = start;
    float wprev = 1e30f;                  // wave's max-pd (inf -> never prune 1st iter)
    unsigned long long wkey = 0ull;       // cached wave candidate
    float wx = 0.f, wy = 0.f, wz = 0.f;
    int par = 0;

    for (int m = 0; m < MPT; ++m) {
        if (tid == 0) s_sel[m] = widx;

        // wave-uniform bbox prune (conservative margin keeps bit-exactness)
        float ex = fmaxf(fmaxf(tnx - fx, fx - txx), 0.f);
        float ey = fmaxf(fmaxf(tny - fy, fy - txy), 0.f);
        float ez = fmaxf(fmaxf(tnz - fz, fz - txz), 0.f);
        float dmin2 = (ex * ex + ey * ey + ez * ez) * 0.99999f;
        if (dmin2 < wprev) {
            float nv = -1.f; int ni = 0x7fffffff;
            float nx = 0.f, ny = 0.f, nz = 0.f;
            #pragma unroll
            for (int k = 0; k < FPS_K; ++k) {
                if (k < L) {
                    float dx = __fsub_rn(px[k], fx);
                    float dy = __fsub_rn(py[k], fy);
                    float dz = __fsub_rn(pz[k], fz);
                    float d  = __fadd_rn(__fadd_rn(__fmul_rn(dx, dx), __fmul_rn(dy, dy)),
                                         __fmul_rn(dz, dz));
                    float nd = fminf(pd[k], d);
                    pd[k] = nd;
                    bool better = (nd > nv) || (nd == nv && pid[k] < ni);
                    if (better) { nv = nd; ni = pid[k]; nx = px[k]; ny = py[k]; nz = pz[k]; }
                }
            }
            unsigned bvb = (nv >= 0.f) ? __float_as_uint(nv) : 0u;
            int bidx = (nv >= 0.f) ? ni : 0x7fffffff;
            // DPP argmax: max val, then min idx among ties (np.argmax semantics)
            unsigned wmaxb = (unsigned)__builtin_amdgcn_readlane((int)dpp_max_u32(bvb), 63);
            int icand = (bvb == wmaxb) ? bidx : 0x7fffffff;
            int wminv = __builtin_amdgcn_readlane(dpp_min_i32(icand), 63);
            unsigned long long mk = __ballot(bvb == wmaxb && bidx == wminv);
            int wl = __ffsll(mk) - 1;     // uniform
            wx = __uint_as_float((unsigned)__builtin_amdgcn_readlane(__float_as_int(nx), wl));
            wy = __uint_as_float((unsigned)__builtin_amdgcn_readlane(__float_as_int(ny), wl));
            wz = __uint_as_float((unsigned)__builtin_amdgcn_readlane(__float_as_int(nz), wl));
            wkey = (((unsigned long long)wmaxb) << 32)
                 | (unsigned long long)(unsigned)(~(unsigned)wminv);
            wprev = __uint_as_float(wmaxb);
        }
        if (lane == 0) {
            s_wkey[par][wv] = wkey;
            s_wc[par][wv][0] = wx; s_wc[par][wv][1] = wy; s_wc[par][wv][2] = wz;
        }
        __syncthreads();
        unsigned long long bk = s_wkey[par][0]; int bw = 0;
        #pragma unroll
        for (int w = 1; w < 8; ++w) {
            unsigned long long o = s_wkey[par][w];
            if (o > bk) { bk = o; bw = w; }
        }
        fx = s_wc[par][bw][0]; fy = s_wc[par][bw][1]; fz = s_wc[par][bw][2];
        widx = (int)(~(unsigned)(bk & 0xffffffffull));
        par ^= 1;
    }
    __syncthreads();
    for (int m = tid; m < MPT; m += FPS_T) fps_idx[b * MPT + m] = s_sel[m];
}

// ---------------------------------------------------------------- gathers
__global__ void k_gather(const float* seed_features, const float* seed_xyz,
                         const int* fps_idx, float* feat_g, float* xyz_g)
{
    int e = blockIdx.x;
    if (e < B_SZ * CSEED) {
        int b = e >> 9, c = e & (CSEED - 1);
        const float* src = seed_features + (size_t)(b * CSEED + c) * N_PTS;
        float* dst = feat_g + (size_t)(b * CSEED + c) * MPT;
        const int* idx = fps_idx + b * MPT;
        for (int m = threadIdx.x; m < MPT; m += blockDim.x) dst[m] = src[idx[m]];
    } else {
        int b = e - B_SZ * CSEED;
        const int* idx = fps_idx + b * MPT;
        for (int m = threadIdx.x; m < MPT; m += blockDim.x) {
            int p = idx[m];
            xyz_g[(size_t)(b * MPT + m) * 3 + 0] = seed_xyz[(size_t)(b * N_PTS + p) * 3 + 0];
            xyz_g[(size_t)(b * MPT + m) * 3 + 1] = seed_xyz[(size_t)(b * N_PTS + p) * 3 + 1];
            xyz_g[(size_t)(b * MPT + m) * 3 + 2] = seed_xyz[(size_t)(b * N_PTS + p) * 3 + 2];
        }
    }
}

// ---------------------------------------------------------------- W2 -> bf16 (same layout)
__global__ void k_w2bf(const float* crop_w2, unsigned short* w2bf) {
    int i = blockIdx.x * blockDim.x + threadIdx.x;
    if (i < 4 * 512 * 256) w2bf[i] = f2bf(crop_w2[i]);
}

// ---------------------------------------------------------------- F1T = feat_g^T * W1f^T + b1
__global__ __launch_bounds__(256) void k_f1(const float* feat_g, const float* crop_w1,
                                            const float* crop_b1, float* f1t)
{
    const int blk = blockIdx.x;
    const int pt = blk & 15;
    const int b  = (blk >> 4) & 1;
    const int s  = blk >> 5;
    const int p0 = pt * 64;
    __shared__ float A[16][64];
    __shared__ float Bm[16][256];
    const int tid = threadIdx.x;
    const int pg = tid & 15, og = tid >> 4;
    float acc[4][16];
    #pragma unroll
    for (int i = 0; i < 4; ++i)
        #pragma unroll
        for (int j = 0; j < 16; ++j) acc[i][j] = 0.f;

    for (int kc = 0; kc < CSEED; kc += 16) {
        __syncthreads();
        {
            int r = tid >> 4, pp = (tid & 15) * 4;
            *(float4*)&A[r][pp] =
                *(const float4*)&feat_g[(size_t)(b * CSEED + kc + r) * MPT + p0 + pp];
            #pragma unroll
            for (int r2 = 0; r2 < 16; ++r2)
                Bm[r2][tid] = crop_w1[(size_t)(s * 256 + tid) * 515 + 3 + kc + r2];
        }
        __syncthreads();
        #pragma unroll
        for (int r = 0; r < 16; ++r) {
            float4 a4 = *(const float4*)&A[r][pg * 4];
            float av[4] = {a4.x, a4.y, a4.z, a4.w};
            float bv[16];
            #pragma unroll
            for (int q = 0; q < 4; ++q) {
                float4 b4 = *(const float4*)&Bm[r][og * 16 + q * 4];
                bv[q*4+0] = b4.x; bv[q*4+1] = b4.y; bv[q*4+2] = b4.z; bv[q*4+3] = b4.w;
            }
            #pragma unroll
            for (int i = 0; i < 4; ++i)
                #pragma unroll
                for (int j = 0; j < 16; ++j)
                    acc[i][j] += av[i] * bv[j];
        }
    }
    #pragma unroll
    for (int i = 0; i < 4; ++i) {
        size_t row = (size_t)((s * B_SZ + b) * MPT + p0 + pg * 4 + i) * 256;
        #pragma unroll
        for (int q = 0; q < 4; ++q) {
            float4 o4;
            o4.x = acc[i][q*4+0] + crop_b1[s*256 + og*16 + q*4+0];
            o4.y = acc[i][q*4+1] + crop_b1[s*256 + og*16 + q*4+1];
            o4.z = acc[i][q*4+2] + crop_b1[s*256 + og*16 + q*4+2];
            o4.w = acc[i][q*4+3] + crop_b1[s*256 + og*16 + q*4+3];
            *(float4*)&f1t[row + og * 16 + q * 4] = o4;
        }
    }
}

// ---------------------------------------------------------------- local coords + neighbor select
__global__ __launch_bounds__(256) void k_select(const float* xyz_g, const float* views_rot,
                                                int* sel_idx, float* sel_xyz)
{
    const int wv = threadIdx.x >> 6;
    const int lane = threadIdx.x & 63;
    const int gj = blockIdx.x * 4 + wv;
    const int b = gj >> 10, j = gj & (MPT - 1);

    const float cx = xyz_g[(size_t)(b * MPT + j) * 3 + 0];
    const float cy = xyz_g[(size_t)(b * MPT + j) * 3 + 1];
    const float cz = xyz_g[(size_t)(b * MPT + j) * 3 + 2];
    const float* R = views_rot + (size_t)(b * MPT + j) * 9;
    const float r00 = R[0], r01 = R[1], r02 = R[2];
    const float r10 = R[3], r11 = R[4], r12 = R[5];
    const float r20 = R[6], r21 = R[7], r22 = R[8];

    const float R2C[4] = { (float)(0.025 * 0.025), (float)(0.0375 * 0.0375),
                           (float)(0.05 * 0.05),   (float)(0.075 * 0.075) };
    const int NSs[4] = {16, 32, 32, 64};

    __shared__ float s_zloc[4][3];
    __shared__ int   s_padk[4][4];
    __shared__ float s_padx[4][4][3];

    int cnt[4] = {0, 0, 0, 0};

    for (int ch = 0; ch < 16; ++ch) {
        int k = ch * 64 + lane;
        float x = xyz_g[(size_t)(b * MPT + k) * 3 + 0];
        float y = xyz_g[(size_t)(b * MPT + k) * 3 + 1];
        float z = xyz_g[(size_t)(b * MPT + k) * 3 + 2];
        float rx = __fsub_rn(x, cx), ry = __fsub_rn(y, cy), rz = __fsub_rn(z, cz);
        float l0 = __fadd_rn(__fadd_rn(__fmul_rn(rx, r00), __fmul_rn(ry, r10)), __fmul_rn(rz, r20));
        float l1 = __fadd_rn(__fadd_rn(__fmul_rn(rx, r01), __fmul_rn(ry, r11)), __fmul_rn(rz, r21));
        float l2 = __fadd_rn(__fadd_rn(__fmul_rn(rx, r02), __fmul_rn(ry, r12)), __fmul_rn(rz, r22));
        float r2 = __fadd_rn(__fmul_rn(l1, l1), __fmul_rn(l2, l2));
        bool inh = (l0 >= HMINF) && (l0 <= HMAXF);
        if (ch == 0 && lane == 0) { s_zloc[wv][0] = l0; s_zloc[wv][1] = l1; s_zloc[wv][2] = l2; }
        #pragma unroll
        for (int sc = 0; sc < 4; ++sc) {
            bool v = inh && (r2 < R2C[sc]);
            unsigned long long bal = __ballot(v);
            int pre = __popcll(bal & ((1ull << lane) - 1ull));
            int p = cnt[sc] + pre;
            if (v && p < NSs[sc]) {
                size_t sb = ((size_t)(sc * B_SZ + b) * MPT + j) * 64 + p;
                sel_idx[sb] = k;
                sel_xyz[sb * 3 + 0] = l0;
                sel_xyz[sb * 3 + 1] = l1;
                sel_xyz[sb * 3 + 2] = l2;
                if (p == 0) {
                    s_padk[wv][sc] = k;
                    s_padx[wv][sc][0] = l0; s_padx[wv][sc][1] = l1; s_padx[wv][sc][2] = l2;
                }
            }
            cnt[sc] += __popcll(bal);
        }
    }
    __syncthreads();
    #pragma unroll
    for (int sc = 0; sc < 4; ++sc) {
        int cs = cnt[sc];
        int pk; float a0, a1, a2;
        if (cs > 0) { pk = s_padk[wv][sc]; a0 = s_padx[wv][sc][0]; a1 = s_padx[wv][sc][1]; a2 = s_padx[wv][sc][2]; }
        else        { pk = 0; a0 = s_zloc[wv][0]; a1 = s_zloc[wv][1]; a2 = s_zloc[wv][2]; }
        for (int n = cs + lane; n < NSs[sc]; n += 64) {
            size_t sb = ((size_t)(sc * B_SZ + b) * MPT + j) * 64 + n;
            sel_idx[sb] = pk;
            sel_xyz[sb * 3 + 0] = a0; sel_xyz[sb * 3 + 1] = a1; sel_xyz[sb * 3 + 2] = a2;
        }
    }
}

// ---------------------------------------------------------------- crop MLP via bf16 MFMA
// 64 cols/block, 4 waves: wave w = col-tile w (16 cols). D[m=col][n=o] so the
// pool axis is D's row: 3 in-reg v_max + xor16/xor32 cross-lane per o-tile.
__global__ __launch_bounds__(256) void k_crop(
        const int s, const int ns, const int log2ns,
        const float* f1t, const float* crop_w1, const unsigned short* w2bf,
        const float* crop_b2, const int* sel_idx, const float* sel_xyz, float* vp_cat)
{
    const int tid = threadIdx.x;
    const int jt = 64 >> log2ns;
    const int nj = MPT / jt;
    const int b = blockIdx.x / nj;
    const int jbase = (blockIdx.x % nj) * jt;

    __shared__ unsigned short h1T[64 * 264];   // [col][c] bf16, stride 264
    __shared__ float w1xa[3 * 256];
    __shared__ float pooled[512 * 4];          // [o][wave]

    for (int i = tid; i < 768; i += 256) {
        int a = i >> 8, o = i & 255;
        w1xa[i] = crop_w1[(size_t)(s * 256 + o) * 515 + a];
    }
    __syncthreads();

    // phase 1: h1 = relu(f1row + W1x*xyz) -> bf16 -> h1T
    {
        const int col = tid & 63;
        const int cq = tid >> 6;
        const int jl = col >> log2ns;
        const int nn = col & (ns - 1);
        const size_t sb = ((size_t)(s * B_SZ + b) * MPT + jbase + jl) * 64 + nn;
        const int p = sel_idx[sb];
        const float gx = sel_xyz[sb * 3 + 0];
        const float gy = sel_xyz[sb * 3 + 1];
        const float gz = sel_xyz[sb * 3 + 2];
        const float* f1row = f1t + (size_t)((s * B_SZ + b) * MPT + p) * 256;
        #pragma unroll
        for (int c4 = 0; c4 < 16; ++c4) {
            int c0 = cq * 64 + c4 * 4;
            float4 fv = *(const float4*)&f1row[c0];
            float v0 = fmaxf(fv.x + w1xa[c0+0]*gx + w1xa[256+c0+0]*gy + w1xa[512+c0+0]*gz, 0.f);
            float v1 = fmaxf(fv.y + w1xa[c0+1]*gx + w1xa[256+c0+1]*gy + w1xa[512+c0+1]*gz, 0.f);
            float v2 = fmaxf(fv.z + w1xa[c0+2]*gx + w1xa[256+c0+2]*gy + w1xa[512+c0+2]*gz, 0.f);
            float v3 = fmaxf(fv.w + w1xa[c0+3]*gx + w1xa[256+c0+3]*gy + w1xa[512+c0+3]*gz, 0.f);
            unsigned lo = (unsigned)f2bf(v0) | ((unsigned)f2bf(v1) << 16);
            unsigned hi = (unsigned)f2bf(v2) | ((unsigned)f2bf(v3) << 16);
            *(uint2*)&h1T[col * 264 + c0] = make_uint2(lo, hi);
        }
    }
    __syncthreads();

    // phase 2: per-wave MFMA over 32 o-tiles
    {
        const int wv = tid >> 6;
        const int lane = tid & 63;
        const int lm = lane & 15, lq = lane >> 4;

        bf16x8 afr[8];                         // h1 A-frags: loaded once
        #pragma unroll
        for (int kk = 0; kk < 8; ++kk)
            afr[kk] = *(const bf16x8*)&h1T[(wv * 16 + lm) * 264 + kk * 32 + lq * 8];

        const unsigned short* wbase = w2bf + (size_t)s * 512 * 256;
        auto ldb = [&](int ot, int kk) -> bf16x8 {
            return *(const bf16x8*)&wbase[(size_t)(ot * 16 + lm) * 256 + kk * 32 + lq * 8];
        };

        bf16x8 bbA[8], bbB[8];
        #pragma unroll
        for (int kk = 0; kk < 8; ++kk) bbA[kk] = ldb(0, kk);

        #pragma unroll 1
        for (int op = 0; op < 16; ++op) {
            const int ot0 = op * 2, ot1 = op * 2 + 1;
            #pragma unroll
            for (int kk = 0; kk < 8; ++kk) bbB[kk] = ldb(ot1, kk);
            {
                f32x4 acc = {0.f, 0.f, 0.f, 0.f};
                #pragma unroll
                for (int kk = 0; kk < 8; ++kk)
                    acc = __builtin_amdgcn_mfma_f32_16x16x32_bf16(afr[kk], bbA[kk], acc, 0, 0, 0);
                float mx = fmaxf(fmaxf(acc[0], acc[1]), fmaxf(acc[2], acc[3]));
                mx = fmaxf(mx, __shfl_xor(mx, 16, 64));
                mx = fmaxf(mx, __shfl_xor(mx, 32, 64));
                if (lane < 16) pooled[(ot0 * 16 + lane) * 4 + wv] = mx;
            }
            if (op < 15) {
                #pragma unroll
                for (int kk = 0; kk < 8; ++kk) bbA[kk] = ldb(ot1 + 1, kk);
            }
            {
                f32x4 acc = {0.f, 0.f, 0.f, 0.f};
                #pragma unroll
                for (int kk = 0; kk < 8; ++kk)
                    acc = __builtin_amdgcn_mfma_f32_16x16x32_bf16(afr[kk], bbB[kk], acc, 0, 0, 0);
                float mx = fmaxf(fmaxf(acc[0], acc[1]), fmaxf(acc[2], acc[3]));
                mx = fmaxf(mx, __shfl_xor(mx, 16, 64));
                mx = fmaxf(mx, __shfl_xor(mx, 32, 64));
                if (lane < 16) pooled[(ot1 * 16 + lane) * 4 + wv] = mx;
            }
        }
    }
    __syncthreads();

    // epilogue: combine wave partials per center, +b2, relu, store
    const int g = ns >> 4;                     // wave-slots per center: 1,2,4
    for (int t = tid; t < 512 * jt; t += 256) {
        int o = t & 511, j2 = t >> 9;
        float v = pooled[o * 4 + j2 * g];
        for (int q = 1; q < g; ++q) v = fmaxf(v, pooled[o * 4 + j2 * g + q]);
        v = fmaxf(v + crop_b2[s * 512 + o], 0.f);
        vp_cat[((size_t)(b * 4 + s) * 512 + o) * MPT + jbase + j2] = v;
    }
}

// ---------------------------------------------------------------- fuse + gate + output
__global__ __launch_bounds__(256) void k_out(
        const float* vp_cat, const float* feat_g,
        const float* fuse_w, const float* fuse_b,
        const float* gate_w, const float* gate_b, float* out)
{
    const int blk = blockIdx.x;
    const int mt = blk & 15, ot = (blk >> 4) & 3, b = blk >> 6;
    const int o0b = ot * 128, m0b = mt * 64;
    __shared__ float A[16 * 128];
    __shared__ float Bm[16 * 64];
    const int tid = threadIdx.x;
    const int og = tid >> 4, mg = tid & 15;
    float acc1[8][4], acc2[8][4];
    #pragma unroll
    for (int i = 0; i < 8; ++i)
        #pragma unroll
        for (int jq = 0; jq < 4; ++jq) { acc1[i][jq] = 0.f; acc2[i][jq] = 0.f; }

    for (int kc = 0; kc < 2048; kc += 16) {
        __syncthreads();
        {
            int oo = tid >> 1, r0 = (tid & 1) * 8;
            const float* srow = fuse_w + (size_t)(o0b + oo) * 2048 + kc + r0;
            float4 u0 = *(const float4*)srow;
            float4 u1 = *(const float4*)(srow + 4);
            A[(r0 + 0) * 128 + oo] = u0.x; A[(r0 + 1) * 128 + oo] = u0.y;
            A[(r0 + 2) * 128 + oo] = u0.z; A[(r0 + 3) * 128 + oo] = u0.w;
            A[(r0 + 4) * 128 + oo] = u1.x; A[(r0 + 5) * 128 + oo] = u1.y;
            A[(r0 + 6) * 128 + oo] = u1.z; A[(r0 + 7) * 128 + oo] = u1.w;
            int r = tid >> 4, mm = (tid & 15) * 4;
            *(float4*)&Bm[r * 64 + mm] =
                *(const float4*)&vp_cat[((size_t)b * 2048 + kc + r) * MPT + m0b + mm];
        }
        __syncthreads();
        #pragma unroll
        for (int r = 0; r < 16; ++r) {
            float4 a0 = *(const float4*)&A[r * 128 + og * 8];
            float4 a1 = *(const float4*)&A[r * 128 + og * 8 + 4];
            float4 bb = *(const float4*)&Bm[r * 64 + mg * 4];
            float av[8] = {a0.x,a0.y,a0.z,a0.w, a1.x,a1.y,a1.z,a1.w};
            float bv[4] = {bb.x, bb.y, bb.z, bb.w};
            #pragma unroll
            for (int oi = 0; oi < 8; ++oi)
                #pragma unroll
                for (int mi = 0; mi < 4; ++mi)
                    acc1[oi][mi] += av[oi] * bv[mi];
        }
    }
    for (int kc = 0; kc < 512; kc += 16) {
        __syncthreads();
        {
            int oo = tid >> 1, r0 = (tid & 1) * 8;
            const float* srow = gate_w + (size_t)(o0b + oo) * 512 + kc + r0;
            float4 u0 = *(const float4*)srow;
            float4 u1 = *(const float4*)(srow + 4);
            A[(r0 + 0) * 128 + oo] = u0.x; A[(r0 + 1) * 128 + oo] = u0.y;
            A[(r0 + 2) * 128 + oo] = u0.z; A[(r0 + 3) * 128 + oo] = u0.w;
            A[(r0 + 4) * 128 + oo] = u1.x; A[(r0 + 5) * 128 + oo] = u1.y;
            A[(r0 + 6) * 128 + oo] = u1.z; A[(r0 + 7) * 128 + oo] = u1.w;
            int r = tid >> 4, mm = (tid & 15) * 4;
            *(float4*)&Bm[r * 64 + mm] =
                *(const float4*)&feat_g[((size_t)b * CSEED + kc + r) * MPT + m0b + mm];
        }
        __syncthreads();
        #pragma unroll
        for (int r = 0; r < 16; ++r) {
            float4 a0 = *(const float4*)&A[r * 128 + og * 8];
            float4 a1 = *(const float4*)&A[r * 128 + og * 8 + 4];
            float4 bb = *(const float4*)&Bm[r * 64 + mg * 4];
            float av[8] = {a0.x,a0.y,a0.z,a0.w, a1.x,a1.y,a1.z,a1.w};
            float bv[4] = {bb.x, bb.y, bb.z, bb.w};
            #pragma unroll
            for (int oi = 0; oi < 8; ++oi)
                #pragma unroll
                for (int mi = 0; mi < 4; ++mi)
                    acc2[oi][mi] += av[oi] * bv[mi];
        }
    }
    #pragma unroll
    for (int oi = 0; oi < 8; ++oi) {
        int o = o0b + og * 8 + oi;
        float fb = fuse_b[o], gb = gate_b[o];
        #pragma unroll
        for (int mi = 0; mi < 4; ++mi) {
            int m = m0b + mg * 4 + mi;
            float f = acc1[oi][mi] + fb;
            float gl = acc2[oi][mi] + gb;
            float gt = 1.f / (1.f + __expf(-gl));
            float fg = feat_g[((size_t)b * CSEED + o) * MPT + m];
            out[((size_t)b * CSEED + o) * MPT + m] = f + gt * fg;
        }
    }
}

// ---------------------------------------------------------------- launcher
extern "C" void kernel_launch(void* const* d_in, const int* in_sizes, int n_in,
                              void* d_out, int out_size, void* d_ws, size_t ws_size,
                              hipStream_t stream) {
    const float* seed_xyz      = (const float*)d_in[0];
    const float* seed_features = (const float*)d_in[1];
    const void*  mask_raw      = d_in[2];
    const float* views_rot     = (const float*)d_in[3];
    const float* crop_w1       = (const float*)d_in[4];
    const float* crop_b1       = (const float*)d_in[5];
    const float* crop_w2       = (const float*)d_in[6];
    const float* crop_b2       = (const float*)d_in[7];
    const float* fuse_w        = (const float*)d_in[8];
    const float* fuse_b        = (const float*)d_in[9];
    const float* gate_w        = (const float*)d_in[10];
    const float* gate_b        = (const float*)d_in[11];
    float* out = (float*)d_out;

    char* ws = (char*)d_ws;
    size_t off = 0;
    auto alloc = [&](size_t bytes) -> void* {
        void* p = ws + off;
        off = (off + bytes + 255) & ~(size_t)255;
        return p;
    };
    int*            mode   = (int*)            alloc(16);
    int*            fpsidx = (int*)            alloc((size_t)B_SZ * MPT * 4);
    float4*         cp     = (float4*)         alloc((size_t)B_SZ * 15008 * 16);
    float*          xyzg   = (float*)          alloc((size_t)B_SZ * MPT * 3 * 4);
    float*          featg  = (float*)          alloc((size_t)B_SZ * CSEED * MPT * 4);
    float*          f1t    = (float*)          alloc((size_t)4 * B_SZ * MPT * 256 * 4);
    int*            selidx = (int*)            alloc((size_t)4 * B_SZ * MPT * 64 * 4);
    float*          selxyz = (float*)          alloc((size_t)4 * B_SZ * MPT * 64 * 3 * 4);
    unsigned short* w2bf   = (unsigned short*) alloc((size_t)4 * 512 * 256 * 2);
    float*          vpcat  = (float*)          alloc((size_t)B_SZ * 4 * 512 * MPT * 4);

    k_detect<<<1, 256, 0, stream>>>((const unsigned int*)mask_raw, mode);
    k_fps<<<B_SZ, FPS_T, 0, stream>>>(mask_raw, mode, seed_xyz, cp, fpsidx);
    k_gather<<<B_SZ * CSEED + B_SZ, 256, 0, stream>>>(seed_features, seed_xyz, fpsidx, featg, xyzg);
    k_w2bf<<<(4 * 512 * 256) / 256, 256, 0, stream>>>(crop_w2, w2bf);
    k_f1<<<128, 256, 0, stream>>>(featg, crop_w1, crop_b1, f1t);
    k_select<<<(B_SZ * MPT) / 4, 256, 0, stream>>>(xyzg, views_rot, selidx, selxyz);
    const int NS[4] = {16, 32, 32, 64};
    const int L2NS[4] = {4, 5, 5, 6};
    for (int s = 0; s < 4; ++s) {
        int jt = 64 >> L2NS[s];
        k_crop<<<B_SZ * (MPT / jt), 256, 0, stream>>>(s, NS[s], L2NS[s],
            f1t, crop_w1, w2bf, crop_b2, selidx, selxyz, vpcat);
    }
    k_out<<<128, 256, 0, stream>>>(vpcat, featg, fuse_w, fuse_b, gate_w, gate_b, out);
}